// Round 4
// baseline (482.095 us; speedup 1.0000x reference)
//
#include <hip/hip_runtime.h>

#define BATCH 8
#define SEQ   2500
#define DIM   128
#define NC    8921

#define LT    64
#define CT    96              // 3 waves x 32 classes
#define NWAVE 3
#define NTILE 93              // ceil(8921/96)
#define NCH   ((SEQ + LT - 1) / LT)   // 40
#define LPAD  (NCH * LT)              // 2560

#define PS_STRIDE 72    // shorts; 144 B rows (9 granules, 16B-aligned)

typedef __attribute__((ext_vector_type(8))) short        short8;
typedef __attribute__((ext_vector_type(4))) float        float4v;
typedef __attribute__((ext_vector_type(4))) unsigned int uint4v;
typedef __attribute__((ext_vector_type(2))) unsigned int uint2v;

// fp32 -> bf16, round-to-nearest-even (finite inputs only)
__device__ __forceinline__ unsigned int f32_to_bf16_bits(float f) {
    unsigned int u = __builtin_bit_cast(unsigned int, f);
    return (u + 0x7FFFu + ((u >> 16) & 1u)) >> 16;
}
__device__ __forceinline__ unsigned int pack_bf16x2(float a, float b) {
    return f32_to_bf16_bits(a) | (f32_to_bf16_bits(b) << 16);
}
__device__ __forceinline__ short to_bf16(float a) {
    return (short)f32_to_bf16_bits(a);
}

// async global->LDS, 16 B per lane; LDS dest = wave-uniform base + lane*16
__device__ __forceinline__ void async_copy16(const short* g, short* l) {
    __builtin_amdgcn_global_load_lds(
        (__attribute__((address_space(1))) void*)(void*)g,
        (__attribute__((address_space(3))) void*)(void*)l,
        16, 0, 0);
}

// ============================ pre-pass ============================
// x fp32 (8,2500,128) -> XB bf16 [8][2560][128], XT bf16 [8][128][2560]
__global__ __launch_bounds__(256)
void lwa_prepass(const float* __restrict__ x,
                 short* __restrict__ XB, short* __restrict__ XT) {
    const int t  = threadIdx.x;
    const int b  = blockIdx.x / NCH;
    const int lt = blockIdx.x % NCH;
    const int l0 = lt * LT;
    const float* xb = x + (size_t)b * SEQ * DIM;

    {   // XB [l][d]
        const int rowg = t >> 5;
        const int col  = (t & 31) * 4;
#pragma unroll
        for (int i = 0; i < 8; ++i) {
            int row = i * 8 + rowg;
            int l   = l0 + row;
            float4v v = (float4v){0.f, 0.f, 0.f, 0.f};
            if (l < SEQ) v = *(const float4v*)(xb + (size_t)l * DIM + col);
            uint2v pv;
            pv[0] = pack_bf16x2(v[0], v[1]);
            pv[1] = pack_bf16x2(v[2], v[3]);
            *(uint2v*)&XB[((size_t)b * LPAD + l) * DIM + col] = pv;
        }
    }
    {   // XT [d][l] via in-register 8x4 transpose
        const int d4  = (t & 31) * 4;
        const int lg8 = (t >> 5) * 8;
        float4v vv[8];
#pragma unroll
        for (int k = 0; k < 8; ++k) {
            int l = l0 + lg8 + k;
            float4v v = (float4v){0.f, 0.f, 0.f, 0.f};
            if (l < SEQ) v = *(const float4v*)(xb + (size_t)l * DIM + d4);
            vv[k] = v;
        }
#pragma unroll
        for (int c = 0; c < 4; ++c) {
            uint4v fu;
            fu[0] = pack_bf16x2(vv[0][c], vv[1][c]);
            fu[1] = pack_bf16x2(vv[2][c], vv[3][c]);
            fu[2] = pack_bf16x2(vv[4][c], vv[5][c]);
            fu[3] = pack_bf16x2(vv[6][c], vv[7][c]);
            *(uint4v*)&XT[((size_t)b * DIM + d4 + c) * LPAD + l0 + lg8] = fu;
        }
    }
}

// ============================ main kernel ============================
// 192 threads = 3 waves, 32 classes/wave, CT=96; grid 8*93=744 (~2.9 blocks/CU,
// 3 fit by LDS -> single round, balanced). Single-buffered DMA staging.
// XOR granule swizzle (granule=16B): Xs phys gran = logical ^ (row&7); same for XTs.
__global__ __launch_bounds__(192, 3)
void lwa_main(const short* __restrict__ XB, const short* __restrict__ XT,
              const float* __restrict__ U, float* __restrict__ out) {
    __shared__ __align__(16) short Xs[LT * DIM];                 // 16 KB
    __shared__ __align__(16) short XTs[DIM * LT];                // 16 KB
    __shared__ __align__(16) short Ps[NWAVE * 32 * PS_STRIDE];   // 13.5 KB

    const int t    = threadIdx.x;
    const int wave = t >> 6;
    const int lane = t & 63;
    const int r    = lane & 15;
    const int q    = lane >> 4;

    const int b  = blockIdx.x % BATCH;            // batch -> XCD/L2 affinity
    const int cw = (blockIdx.x / BATCH) * CT + wave * 32;

    short* Pw = &Ps[wave * 32 * PS_STRIDE];

    // ---- precompute per-issue lane byte-offsets (wave w takes issues i=w+3j) ----
    unsigned int offs[11];
#pragma unroll
    for (int j = 0; j < 11; ++j) {
        int i = wave + 3 * j;
        unsigned int off = 0;
        if (i < 32) {
            if (i < 16) {            // Xs granules: 16/row
                int g   = i * 64 + lane;
                int row = g >> 4;
                int gc  = (g & 15) ^ (row & 7);
                off = (unsigned)(row * DIM + gc * 8) * 2u;
            } else {                 // XT granules: 8/row
                int g    = (i - 16) * 64 + lane;
                int rowd = g >> 3;
                int gc   = (g & 7) ^ (rowd & 7);
                off = (unsigned)(rowd * LPAD + gc * 8) * 2u;
            }
        }
        offs[j] = off;
    }
    const char* srcA0 = (const char*)(XB + (size_t)b * LPAD * DIM);  // + ch*LT*DIM*2
    const char* srcB0 = (const char*)(XT + (size_t)b * DIM * LPAD);  // + ch*LT*2

    // ---- U fragments in registers: A[m=r][k=q*8+j] ----
    short8 Uf[2][4];
#pragma unroll
    for (int mt = 0; mt < 2; ++mt) {
        int c = cw + mt * 16 + r;
        if (c >= NC) c = NC - 1;                  // clamp; stores masked later
        const float* up = U + (size_t)c * DIM + q * 8;
#pragma unroll
        for (int k = 0; k < 4; ++k) {
            float4v a  = *(const float4v*)(up + k * 32);
            float4v b2 = *(const float4v*)(up + k * 32 + 4);
            uint4v fu;
            fu[0] = pack_bf16x2(a[0], a[1]);
            fu[1] = pack_bf16x2(a[2], a[3]);
            fu[2] = pack_bf16x2(b2[0], b2[1]);
            fu[3] = pack_bf16x2(b2[2], b2[3]);
            Uf[mt][k] = __builtin_bit_cast(short8, fu);
        }
    }

    float4v Oacc[2][8];
#pragma unroll
    for (int mt = 0; mt < 2; ++mt)
#pragma unroll
        for (int nt = 0; nt < 8; ++nt)
            Oacc[mt][nt] = (float4v){0.f, 0.f, 0.f, 0.f};

    float sume[2][4] = {{0.f, 0.f, 0.f, 0.f}, {0.f, 0.f, 0.f, 0.f}};

    // ---- stage chunk 0 ----
#pragma unroll
    for (int j = 0; j < 11; ++j) {
        int i = wave + 3 * j;
        if (i < 16)       async_copy16((const short*)(srcA0 + offs[j]), &Xs[i * 512]);
        else if (i < 32)  async_copy16((const short*)(srcB0 + offs[j]), &XTs[(i - 16) * 512]);
    }

    for (int ch = 0; ch < NCH; ++ch) {
        const int l0 = ch * LT;
        __syncthreads();   // drains DMA (vmcnt) -> chunk ch staged

        // ---- GEMM1: S[c][l] = U . X^T (B from swizzled Xs) ----
        float4v S[2][4];
#pragma unroll
        for (int mt = 0; mt < 2; ++mt)
#pragma unroll
            for (int nt = 0; nt < 4; ++nt)
                S[mt][nt] = (float4v){0.f, 0.f, 0.f, 0.f};
#pragma unroll
        for (int k = 0; k < 4; ++k) {
            short8 Bf[4];
#pragma unroll
            for (int nt = 0; nt < 4; ++nt)
                Bf[nt] = *(const short8*)&Xs[(nt * 16 + r) * DIM +
                                             (((k * 4 + q) ^ (r & 7)) << 3)];
#pragma unroll
            for (int mt = 0; mt < 2; ++mt)
#pragma unroll
                for (int nt = 0; nt < 4; ++nt)
                    S[mt][nt] = __builtin_amdgcn_mfma_f32_16x16x32_bf16(
                        Uf[mt][k], Bf[nt], S[mt][nt], 0, 0, 0);
        }

        // ---- exp (no max-sub: |s| <~ 5), masked sumexp, P -> LDS (both mt) ----
#pragma unroll
        for (int mt = 0; mt < 2; ++mt)
#pragma unroll
            for (int nt = 0; nt < 4; ++nt) {
                const int  l     = l0 + nt * 16 + r;
                const bool valid = (l < SEQ);
#pragma unroll
                for (int reg = 0; reg < 4; ++reg) {
                    float e = __expf(S[mt][nt][reg]);
                    e = valid ? e : 0.f;
                    sume[mt][reg] += e;
                    Pw[(mt * 16 + q * 4 + reg) * PS_STRIDE + nt * 16 + r] = to_bf16(e);
                }
            }
        // Pw wave-private: compiler orders write->read via lgkmcnt

        // ---- GEMM2: O[c][d] += P . X, kk-outer (Bf read once) ----
#pragma unroll
        for (int kk = 0; kk < 2; ++kk) {
            short8 Af[2];
#pragma unroll
            for (int mt = 0; mt < 2; ++mt)
                Af[mt] = *(const short8*)&Pw[(mt * 16 + r) * PS_STRIDE + kk * 32 + q * 8];
#pragma unroll
            for (int nt = 0; nt < 8; ++nt) {
                short8 Bf = *(const short8*)&XTs[(nt * 16 + r) * LT +
                                                 (((kk * 4 + q) ^ (r & 7)) << 3)];
#pragma unroll
                for (int mt = 0; mt < 2; ++mt)
                    Oacc[mt][nt] = __builtin_amdgcn_mfma_f32_16x16x32_bf16(
                        Af[mt], Bf, Oacc[mt][nt], 0, 0, 0);
            }
        }

        __syncthreads();   // all reads of chunk ch done
        if (ch + 1 < NCH) {
            const char* srcA = srcA0 + (size_t)(ch + 1) * LT * DIM * 2;
            const char* srcB = srcB0 + (size_t)(ch + 1) * LT * 2;
#pragma unroll
            for (int j = 0; j < 11; ++j) {
                int i = wave + 3 * j;
                if (i < 16)       async_copy16((const short*)(srcA + offs[j]), &Xs[i * 512]);
                else if (i < 32)  async_copy16((const short*)(srcB + offs[j]), &XTs[(i - 16) * 512]);
            }
        }
    }

    // ---- reduce sumexp across the 16 l-lanes ----
#pragma unroll
    for (int mt = 0; mt < 2; ++mt)
#pragma unroll
        for (int reg = 0; reg < 4; ++reg) {
            float s = sume[mt][reg];
            s += __shfl_xor(s, 1, 64);
            s += __shfl_xor(s, 2, 64);
            s += __shfl_xor(s, 4, 64);
            s += __shfl_xor(s, 8, 64);
            sume[mt][reg] = 1.0f / s;
        }

    // ---- normalize + store: c = cw + mt*16 + q*4 + reg, d = nt*16 + r ----
#pragma unroll
    for (int mt = 0; mt < 2; ++mt) {
#pragma unroll
        for (int reg = 0; reg < 4; ++reg) {
            const int c = cw + mt * 16 + q * 4 + reg;
            if (c < NC) {
                const float inv = sume[mt][reg];
                float* op = out + ((size_t)b * NC + c) * DIM + r;
#pragma unroll
                for (int nt = 0; nt < 8; ++nt)
                    op[nt * 16] = Oacc[mt][nt][reg] * inv;
            }
        }
    }
}

// ============================ fallback (R2, verified) ============================
#define XS_STRIDE 136
#define XT_STRIDE 72

__global__ __launch_bounds__(256, 2)
void lwa_fallback(const float* __restrict__ x,
                  const float* __restrict__ U,
                  float* __restrict__ out) {
    __shared__ __align__(16) short Xs[LT * XS_STRIDE];
    __shared__ __align__(16) short XTs[DIM * XT_STRIDE];
    __shared__ __align__(16) short Psf[4 * 32 * XT_STRIDE];

    const int t    = threadIdx.x;
    const int wave = t >> 6;
    const int lane = t & 63;
    const int r    = lane & 15;
    const int q    = lane >> 4;

    const int b  = blockIdx.x % BATCH;
    const int cw = (blockIdx.x / BATCH) * 128 + wave * 32;

    const float* xb = x + (size_t)b * SEQ * DIM;
    short* Pw = &Psf[wave * 32 * XT_STRIDE];

    short8 Uf[2][4];
#pragma unroll
    for (int mt = 0; mt < 2; ++mt) {
        int c = cw + mt * 16 + r;
        if (c >= NC) c = NC - 1;
        const float* up = U + (size_t)c * DIM + q * 8;
#pragma unroll
        for (int k = 0; k < 4; ++k) {
            float4v a  = *(const float4v*)(up + k * 32);
            float4v b2 = *(const float4v*)(up + k * 32 + 4);
            uint4v fu;
            fu[0] = pack_bf16x2(a[0], a[1]);
            fu[1] = pack_bf16x2(a[2], a[3]);
            fu[2] = pack_bf16x2(b2[0], b2[1]);
            fu[3] = pack_bf16x2(b2[2], b2[3]);
            Uf[mt][k] = __builtin_bit_cast(short8, fu);
        }
    }

    float4v Oacc[2][8];
#pragma unroll
    for (int mt = 0; mt < 2; ++mt)
#pragma unroll
        for (int nt = 0; nt < 8; ++nt)
            Oacc[mt][nt] = (float4v){0.f, 0.f, 0.f, 0.f};

    float sume[2][4] = {{0.f, 0.f, 0.f, 0.f}, {0.f, 0.f, 0.f, 0.f}};

    for (int ch = 0; ch < NCH; ++ch) {
        const int l0 = ch * LT;
        __syncthreads();
        {
            const int rowg = t >> 5;
            const int col  = (t & 31) * 4;
#pragma unroll
            for (int i = 0; i < 8; ++i) {
                int row = i * 8 + rowg;
                int l   = l0 + row;
                float4v v = (float4v){0.f, 0.f, 0.f, 0.f};
                if (l < SEQ) v = *(const float4v*)(xb + (size_t)l * DIM + col);
                uint2v pv;
                pv[0] = pack_bf16x2(v[0], v[1]);
                pv[1] = pack_bf16x2(v[2], v[3]);
                *(uint2v*)&Xs[row * XS_STRIDE + col] = pv;
            }
        }
        {
            const int d4  = (t & 31) * 4;
            const int lg8 = (t >> 5) * 8;
            float4v vv[8];
#pragma unroll
            for (int k = 0; k < 8; ++k) {
                int l = l0 + lg8 + k;
                float4v v = (float4v){0.f, 0.f, 0.f, 0.f};
                if (l < SEQ) v = *(const float4v*)(xb + (size_t)l * DIM + d4);
                vv[k] = v;
            }
#pragma unroll
            for (int c = 0; c < 4; ++c) {
                uint4v fu;
                fu[0] = pack_bf16x2(vv[0][c], vv[1][c]);
                fu[1] = pack_bf16x2(vv[2][c], vv[3][c]);
                fu[2] = pack_bf16x2(vv[4][c], vv[5][c]);
                fu[3] = pack_bf16x2(vv[6][c], vv[7][c]);
                *(uint4v*)&XTs[(d4 + c) * XT_STRIDE + lg8] = fu;
            }
        }
        __syncthreads();

        float4v S[2][4];
#pragma unroll
        for (int mt = 0; mt < 2; ++mt)
#pragma unroll
            for (int nt = 0; nt < 4; ++nt)
                S[mt][nt] = (float4v){0.f, 0.f, 0.f, 0.f};
#pragma unroll
        for (int k = 0; k < 4; ++k) {
            short8 Bf[4];
#pragma unroll
            for (int nt = 0; nt < 4; ++nt)
                Bf[nt] = *(const short8*)&Xs[(nt * 16 + r) * XS_STRIDE + k * 32 + q * 8];
#pragma unroll
            for (int mt = 0; mt < 2; ++mt)
#pragma unroll
                for (int nt = 0; nt < 4; ++nt)
                    S[mt][nt] = __builtin_amdgcn_mfma_f32_16x16x32_bf16(
                        Uf[mt][k], Bf[nt], S[mt][nt], 0, 0, 0);
        }

#pragma unroll
        for (int mt = 0; mt < 2; ++mt)
#pragma unroll
            for (int nt = 0; nt < 4; ++nt) {
                const int  l     = l0 + nt * 16 + r;
                const bool valid = (l < SEQ);
#pragma unroll
                for (int reg = 0; reg < 4; ++reg) {
                    float e = __expf(S[mt][nt][reg]);
                    e = valid ? e : 0.f;
                    sume[mt][reg] += e;
                    Pw[(mt * 16 + q * 4 + reg) * XT_STRIDE + nt * 16 + r] = to_bf16(e);
                }
            }

#pragma unroll
        for (int k = 0; k < 2; ++k) {
            short8 Af[2];
#pragma unroll
            for (int mt = 0; mt < 2; ++mt)
                Af[mt] = *(const short8*)&Pw[(mt * 16 + r) * XT_STRIDE + k * 32 + q * 8];
#pragma unroll
            for (int nt = 0; nt < 8; ++nt) {
                short8 Bf = *(const short8*)&XTs[(nt * 16 + r) * XT_STRIDE + k * 32 + q * 8];
#pragma unroll
                for (int mt = 0; mt < 2; ++mt)
                    Oacc[mt][nt] = __builtin_amdgcn_mfma_f32_16x16x32_bf16(
                        Af[mt], Bf, Oacc[mt][nt], 0, 0, 0);
            }
        }
    }

#pragma unroll
    for (int mt = 0; mt < 2; ++mt)
#pragma unroll
        for (int reg = 0; reg < 4; ++reg) {
            float s = sume[mt][reg];
            s += __shfl_xor(s, 1, 64);
            s += __shfl_xor(s, 2, 64);
            s += __shfl_xor(s, 4, 64);
            s += __shfl_xor(s, 8, 64);
            sume[mt][reg] = 1.0f / s;
        }

#pragma unroll
    for (int mt = 0; mt < 2; ++mt) {
#pragma unroll
        for (int reg = 0; reg < 4; ++reg) {
            const int c = cw + mt * 16 + q * 4 + reg;
            if (c < NC) {
                const float inv = sume[mt][reg];
                float* op = out + ((size_t)b * NC + c) * DIM + r;
#pragma unroll
                for (int nt = 0; nt < 8; ++nt)
                    op[nt * 16] = Oacc[mt][nt][reg] * inv;
            }
        }
    }
}

extern "C" void kernel_launch(void* const* d_in, const int* in_sizes, int n_in,
                              void* d_out, int out_size, void* d_ws, size_t ws_size,
                              hipStream_t stream) {
    const float* x = (const float*)d_in[0];   // (8, 2500, 128) fp32
    const float* U = (const float*)d_in[1];   // (8921, 128) fp32
    float* out = (float*)d_out;               // (8, 8921, 128) fp32

    const size_t need = 2 * (size_t)BATCH * LPAD * DIM * sizeof(short);  // 10.5 MB
    if (ws_size >= need) {
        short* XB = (short*)d_ws;
        short* XT = XB + (size_t)BATCH * LPAD * DIM;
        lwa_prepass<<<dim3(BATCH * NCH), dim3(256), 0, stream>>>(x, XB, XT);
        lwa_main<<<dim3(BATCH * NTILE), dim3(192), 0, stream>>>(XB, XT, U, out);
    } else {
        const int nblocks = BATCH * ((NC + 127) / 128);   // 560
        lwa_fallback<<<dim3(nblocks), dim3(256), 0, stream>>>(x, U, out);
    }
}

// Round 5
// 243.501 us; speedup vs baseline: 1.9798x; 1.9798x over previous
//
#include <hip/hip_runtime.h>

#define BATCH 8
#define SEQ   2500
#define DIM   128
#define NC    8921

#define LT    64
#define CT    128
#define NWAVE 4
#define NCH   ((SEQ + LT - 1) / LT)   // 40
#define LPAD  (NCH * LT)              // 2560

#define PS_STRIDE 72    // shorts; 144 B rows

typedef __attribute__((ext_vector_type(8))) short        short8;
typedef __attribute__((ext_vector_type(4))) float        float4v;
typedef __attribute__((ext_vector_type(4))) unsigned int uint4v;
typedef __attribute__((ext_vector_type(2))) unsigned int uint2v;

// fp32 -> bf16, round-to-nearest-even (finite inputs only)
__device__ __forceinline__ unsigned int f32_to_bf16_bits(float f) {
    unsigned int u = __builtin_bit_cast(unsigned int, f);
    return (u + 0x7FFFu + ((u >> 16) & 1u)) >> 16;
}
__device__ __forceinline__ unsigned int pack_bf16x2(float a, float b) {
    return f32_to_bf16_bits(a) | (f32_to_bf16_bits(b) << 16);
}
__device__ __forceinline__ short to_bf16(float a) {
    return (short)f32_to_bf16_bits(a);
}

// async global->LDS, 16 B per lane; LDS dest = wave-uniform base + lane*16
__device__ __forceinline__ void async_copy16(const short* g, short* l) {
    __builtin_amdgcn_global_load_lds(
        (__attribute__((address_space(1))) void*)(void*)g,
        (__attribute__((address_space(3))) void*)(void*)l,
        16, 0, 0);
}

// ============================ pre-pass ============================
// x fp32 (8,2500,128) -> XB bf16 [8][2560][128], XT bf16 [8][128][2560]
__global__ __launch_bounds__(256)
void lwa_prepass(const float* __restrict__ x,
                 short* __restrict__ XB, short* __restrict__ XT) {
    const int t  = threadIdx.x;
    const int b  = blockIdx.x / NCH;
    const int lt = blockIdx.x % NCH;
    const int l0 = lt * LT;
    const float* xb = x + (size_t)b * SEQ * DIM;

    {   // XB [l][d]
        const int rowg = t >> 5;
        const int col  = (t & 31) * 4;
#pragma unroll
        for (int i = 0; i < 8; ++i) {
            int row = i * 8 + rowg;
            int l   = l0 + row;
            float4v v = (float4v){0.f, 0.f, 0.f, 0.f};
            if (l < SEQ) v = *(const float4v*)(xb + (size_t)l * DIM + col);
            uint2v pv;
            pv[0] = pack_bf16x2(v[0], v[1]);
            pv[1] = pack_bf16x2(v[2], v[3]);
            *(uint2v*)&XB[((size_t)b * LPAD + l) * DIM + col] = pv;
        }
    }
    {   // XT [d][l] via in-register 8x4 transpose
        const int d4  = (t & 31) * 4;
        const int lg8 = (t >> 5) * 8;
        float4v vv[8];
#pragma unroll
        for (int k = 0; k < 8; ++k) {
            int l = l0 + lg8 + k;
            float4v v = (float4v){0.f, 0.f, 0.f, 0.f};
            if (l < SEQ) v = *(const float4v*)(xb + (size_t)l * DIM + d4);
            vv[k] = v;
        }
#pragma unroll
        for (int c = 0; c < 4; ++c) {
            uint4v fu;
            fu[0] = pack_bf16x2(vv[0][c], vv[1][c]);
            fu[1] = pack_bf16x2(vv[2][c], vv[3][c]);
            fu[2] = pack_bf16x2(vv[4][c], vv[5][c]);
            fu[3] = pack_bf16x2(vv[6][c], vv[7][c]);
            *(uint4v*)&XT[((size_t)b * DIM + d4 + c) * LPAD + l0 + lg8] = fu;
        }
    }
}

// ============================ main kernel ============================
// R3 structure (proven): 256 thr, double-buffered DMA staging, XOR granule
// swizzle (granule=16B, phys = logical ^ (row&7)).
// R5 change: XTs B-fragments hoisted to registers once per chunk (16 b128
// instead of 32), mt-split P roundtrip against register-cached Bf.
__global__ __launch_bounds__(256, 2)
void lwa_main(const short* __restrict__ XB, const short* __restrict__ XT,
              const float* __restrict__ U, float* __restrict__ out) {
    __shared__ __align__(16) short XsB[2][LT * DIM];    // 2 x 16 KB
    __shared__ __align__(16) short XTsB[2][DIM * LT];   // 2 x 16 KB
    __shared__ __align__(16) short Ps[NWAVE * 16 * PS_STRIDE];  // 9216 B

    const int t    = threadIdx.x;
    const int wave = t >> 6;
    const int lane = t & 63;
    const int r    = lane & 15;
    const int q    = lane >> 4;

    const int b  = blockIdx.x % BATCH;            // batch -> XCD/L2 affinity
    const int cw = (blockIdx.x / BATCH) * CT + wave * 32;

    short* Pw = &Ps[wave * 16 * PS_STRIDE];

    // ---- staging source pointers (per lane, chunk 0) ----
    const short* gXs[4];
    const short* gXT[4];
#pragma unroll
    for (int j = 0; j < 4; ++j) {
        int p    = (wave * 4 + j) * 64 + lane;   // granule index in chunk
        int row  = p >> 4;                        // Xs: 16 granules/row
        int gcol = (p & 15) ^ (row & 7);
        gXs[j] = XB + (size_t)b * LPAD * DIM + row * DIM + gcol * 8;
        int rowd  = p >> 3;                       // XT: 8 granules/row
        int gcol2 = (p & 7) ^ (rowd & 7);
        gXT[j] = XT + ((size_t)b * DIM + rowd) * LPAD + gcol2 * 8;
    }

    // ---- U fragments in registers: A[m=r][k=q*8+j] ----
    short8 Uf[2][4];
#pragma unroll
    for (int mt = 0; mt < 2; ++mt) {
        int c = cw + mt * 16 + r;
        if (c >= NC) c = NC - 1;                  // clamp; stores masked later
        const float* up = U + (size_t)c * DIM + q * 8;
#pragma unroll
        for (int k = 0; k < 4; ++k) {
            float4v a  = *(const float4v*)(up + k * 32);
            float4v b2 = *(const float4v*)(up + k * 32 + 4);
            uint4v fu;
            fu[0] = pack_bf16x2(a[0], a[1]);
            fu[1] = pack_bf16x2(a[2], a[3]);
            fu[2] = pack_bf16x2(b2[0], b2[1]);
            fu[3] = pack_bf16x2(b2[2], b2[3]);
            Uf[mt][k] = __builtin_bit_cast(short8, fu);
        }
    }

    float4v Oacc[2][8];
#pragma unroll
    for (int mt = 0; mt < 2; ++mt)
#pragma unroll
        for (int nt = 0; nt < 8; ++nt)
            Oacc[mt][nt] = (float4v){0.f, 0.f, 0.f, 0.f};

    float sume[2][4] = {{0.f, 0.f, 0.f, 0.f}, {0.f, 0.f, 0.f, 0.f}};

    // ---- prefetch chunk 0 into buf 0 ----
#pragma unroll
    for (int j = 0; j < 4; ++j) {
        async_copy16(gXs[j], &XsB[0][(wave * 4 + j) * 512]);
        async_copy16(gXT[j], &XTsB[0][(wave * 4 + j) * 512]);
    }
    __syncthreads();   // drains vmcnt -> chunk 0 staged

    for (int ch = 0; ch < NCH; ++ch) {
        const int cb = ch & 1;
        const int l0 = ch * LT;

        // ---- issue async prefetch of chunk ch+1 (hidden under compute) ----
        if (ch + 1 < NCH) {
            const int nb = (ch + 1) & 1;
#pragma unroll
            for (int j = 0; j < 4; ++j) {
                async_copy16(gXs[j] + (size_t)(ch + 1) * (LT * DIM),
                             &XsB[nb][(wave * 4 + j) * 512]);
                async_copy16(gXT[j] + (size_t)(ch + 1) * LT,
                             &XTsB[nb][(wave * 4 + j) * 512]);
            }
        }

        // ---- GEMM1: S[c][l] = U . X^T (B from swizzled XsB) ----
        const short* Xc = &XsB[cb][0];
        float4v S[2][4];
#pragma unroll
        for (int mt = 0; mt < 2; ++mt)
#pragma unroll
            for (int nt = 0; nt < 4; ++nt)
                S[mt][nt] = (float4v){0.f, 0.f, 0.f, 0.f};
#pragma unroll
        for (int k = 0; k < 4; ++k) {
            short8 Bf[4];
#pragma unroll
            for (int nt = 0; nt < 4; ++nt)
                Bf[nt] = *(const short8*)&Xc[(nt * 16 + r) * DIM +
                                             (((k * 4 + q) ^ (r & 7)) << 3)];
#pragma unroll
            for (int mt = 0; mt < 2; ++mt)
#pragma unroll
                for (int nt = 0; nt < 4; ++nt)
                    S[mt][nt] = __builtin_amdgcn_mfma_f32_16x16x32_bf16(
                        Uf[mt][k], Bf[nt], S[mt][nt], 0, 0, 0);
        }

        // ---- load ALL XTs B-fragments for this chunk into registers (16 b128) ----
        const short* XTc = &XTsB[cb][0];
        short8 Bf2[2][8];
#pragma unroll
        for (int kk = 0; kk < 2; ++kk)
#pragma unroll
            for (int nt = 0; nt < 8; ++nt)
                Bf2[kk][nt] = *(const short8*)&XTc[(nt * 16 + r) * LT +
                                                   (((kk * 4 + q) ^ (r & 7)) << 3)];

        // ---- per mt-half: exp -> P(LDS, wave-private) -> GEMM2 vs cached Bf ----
#pragma unroll
        for (int mt = 0; mt < 2; ++mt) {
#pragma unroll
            for (int nt = 0; nt < 4; ++nt) {
                const int  l     = l0 + nt * 16 + r;
                const bool valid = (l < SEQ);
#pragma unroll
                for (int reg = 0; reg < 4; ++reg) {
                    float e = __expf(S[mt][nt][reg]);
                    e = valid ? e : 0.f;
                    sume[mt][reg] += e;
                    Pw[(q * 4 + reg) * PS_STRIDE + nt * 16 + r] = to_bf16(e);
                }
            }
            short8 Af[2];
#pragma unroll
            for (int kk = 0; kk < 2; ++kk)
                Af[kk] = *(const short8*)&Pw[r * PS_STRIDE + kk * 32 + q * 8];
#pragma unroll
            for (int kk = 0; kk < 2; ++kk)
#pragma unroll
                for (int nt = 0; nt < 8; ++nt)
                    Oacc[mt][nt] = __builtin_amdgcn_mfma_f32_16x16x32_bf16(
                        Af[kk], Bf2[kk][nt], Oacc[mt][nt], 0, 0, 0);
        }

        __syncthreads();   // all reads of chunk ch done; prefetch already complete
    }

    // ---- reduce sumexp across the 16 l-lanes ----
#pragma unroll
    for (int mt = 0; mt < 2; ++mt)
#pragma unroll
        for (int reg = 0; reg < 4; ++reg) {
            float s = sume[mt][reg];
            s += __shfl_xor(s, 1, 64);
            s += __shfl_xor(s, 2, 64);
            s += __shfl_xor(s, 4, 64);
            s += __shfl_xor(s, 8, 64);
            sume[mt][reg] = 1.0f / s;
        }

    // ---- normalize + store: c = cw + mt*16 + q*4 + reg, d = nt*16 + r ----
#pragma unroll
    for (int mt = 0; mt < 2; ++mt) {
#pragma unroll
        for (int reg = 0; reg < 4; ++reg) {
            const int c = cw + mt * 16 + q * 4 + reg;
            if (c < NC) {
                const float inv = sume[mt][reg];
                float* op = out + ((size_t)b * NC + c) * DIM + r;
#pragma unroll
                for (int nt = 0; nt < 8; ++nt)
                    op[nt * 16] = Oacc[mt][nt][reg] * inv;
            }
        }
    }
}

// ============================ fallback (R2, verified) ============================
#define XS_STRIDE 136
#define XT_STRIDE 72

__global__ __launch_bounds__(256, 2)
void lwa_fallback(const float* __restrict__ x,
                  const float* __restrict__ U,
                  float* __restrict__ out) {
    __shared__ __align__(16) short Xs[LT * XS_STRIDE];
    __shared__ __align__(16) short XTs[DIM * XT_STRIDE];
    __shared__ __align__(16) short Psf[4 * 32 * XT_STRIDE];

    const int t    = threadIdx.x;
    const int wave = t >> 6;
    const int lane = t & 63;
    const int r    = lane & 15;
    const int q    = lane >> 4;

    const int b  = blockIdx.x % BATCH;
    const int cw = (blockIdx.x / BATCH) * 128 + wave * 32;

    const float* xb = x + (size_t)b * SEQ * DIM;
    short* Pw = &Psf[wave * 32 * XT_STRIDE];

    short8 Uf[2][4];
#pragma unroll
    for (int mt = 0; mt < 2; ++mt) {
        int c = cw + mt * 16 + r;
        if (c >= NC) c = NC - 1;
        const float* up = U + (size_t)c * DIM + q * 8;
#pragma unroll
        for (int k = 0; k < 4; ++k) {
            float4v a  = *(const float4v*)(up + k * 32);
            float4v b2 = *(const float4v*)(up + k * 32 + 4);
            uint4v fu;
            fu[0] = pack_bf16x2(a[0], a[1]);
            fu[1] = pack_bf16x2(a[2], a[3]);
            fu[2] = pack_bf16x2(b2[0], b2[1]);
            fu[3] = pack_bf16x2(b2[2], b2[3]);
            Uf[mt][k] = __builtin_bit_cast(short8, fu);
        }
    }

    float4v Oacc[2][8];
#pragma unroll
    for (int mt = 0; mt < 2; ++mt)
#pragma unroll
        for (int nt = 0; nt < 8; ++nt)
            Oacc[mt][nt] = (float4v){0.f, 0.f, 0.f, 0.f};

    float sume[2][4] = {{0.f, 0.f, 0.f, 0.f}, {0.f, 0.f, 0.f, 0.f}};

    for (int ch = 0; ch < NCH; ++ch) {
        const int l0 = ch * LT;
        __syncthreads();
        {
            const int rowg = t >> 5;
            const int col  = (t & 31) * 4;
#pragma unroll
            for (int i = 0; i < 8; ++i) {
                int row = i * 8 + rowg;
                int l   = l0 + row;
                float4v v = (float4v){0.f, 0.f, 0.f, 0.f};
                if (l < SEQ) v = *(const float4v*)(xb + (size_t)l * DIM + col);
                uint2v pv;
                pv[0] = pack_bf16x2(v[0], v[1]);
                pv[1] = pack_bf16x2(v[2], v[3]);
                *(uint2v*)&Xs[row * XS_STRIDE + col] = pv;
            }
        }
        {
            const int d4  = (t & 31) * 4;
            const int lg8 = (t >> 5) * 8;
            float4v vv[8];
#pragma unroll
            for (int k = 0; k < 8; ++k) {
                int l = l0 + lg8 + k;
                float4v v = (float4v){0.f, 0.f, 0.f, 0.f};
                if (l < SEQ) v = *(const float4v*)(xb + (size_t)l * DIM + d4);
                vv[k] = v;
            }
#pragma unroll
            for (int c = 0; c < 4; ++c) {
                uint4v fu;
                fu[0] = pack_bf16x2(vv[0][c], vv[1][c]);
                fu[1] = pack_bf16x2(vv[2][c], vv[3][c]);
                fu[2] = pack_bf16x2(vv[4][c], vv[5][c]);
                fu[3] = pack_bf16x2(vv[6][c], vv[7][c]);
                *(uint4v*)&XTs[(d4 + c) * XT_STRIDE + lg8] = fu;
            }
        }
        __syncthreads();

        float4v S[2][4];
#pragma unroll
        for (int mt = 0; mt < 2; ++mt)
#pragma unroll
            for (int nt = 0; nt < 4; ++nt)
                S[mt][nt] = (float4v){0.f, 0.f, 0.f, 0.f};
#pragma unroll
        for (int k = 0; k < 4; ++k) {
            short8 Bf[4];
#pragma unroll
            for (int nt = 0; nt < 4; ++nt)
                Bf[nt] = *(const short8*)&Xs[(nt * 16 + r) * XS_STRIDE + k * 32 + q * 8];
#pragma unroll
            for (int mt = 0; mt < 2; ++mt)
#pragma unroll
                for (int nt = 0; nt < 4; ++nt)
                    S[mt][nt] = __builtin_amdgcn_mfma_f32_16x16x32_bf16(
                        Uf[mt][k], Bf[nt], S[mt][nt], 0, 0, 0);
        }

#pragma unroll
        for (int mt = 0; mt < 2; ++mt)
#pragma unroll
            for (int nt = 0; nt < 4; ++nt) {
                const int  l     = l0 + nt * 16 + r;
                const bool valid = (l < SEQ);
#pragma unroll
                for (int reg = 0; reg < 4; ++reg) {
                    float e = __expf(S[mt][nt][reg]);
                    e = valid ? e : 0.f;
                    sume[mt][reg] += e;
                    Pw[(mt * 16 + q * 4 + reg) * XT_STRIDE + nt * 16 + r] = to_bf16(e);
                }
            }

#pragma unroll
        for (int k = 0; k < 2; ++k) {
            short8 Af[2];
#pragma unroll
            for (int mt = 0; mt < 2; ++mt)
                Af[mt] = *(const short8*)&Pw[(mt * 16 + r) * XT_STRIDE + k * 32 + q * 8];
#pragma unroll
            for (int nt = 0; nt < 8; ++nt) {
                short8 Bf = *(const short8*)&XTs[(nt * 16 + r) * XT_STRIDE + k * 32 + q * 8];
#pragma unroll
                for (int mt = 0; mt < 2; ++mt)
                    Oacc[mt][nt] = __builtin_amdgcn_mfma_f32_16x16x32_bf16(
                        Af[mt], Bf, Oacc[mt][nt], 0, 0, 0);
            }
        }
    }

#pragma unroll
    for (int mt = 0; mt < 2; ++mt)
#pragma unroll
        for (int reg = 0; reg < 4; ++reg) {
            float s = sume[mt][reg];
            s += __shfl_xor(s, 1, 64);
            s += __shfl_xor(s, 2, 64);
            s += __shfl_xor(s, 4, 64);
            s += __shfl_xor(s, 8, 64);
            sume[mt][reg] = 1.0f / s;
        }

#pragma unroll
    for (int mt = 0; mt < 2; ++mt) {
#pragma unroll
        for (int reg = 0; reg < 4; ++reg) {
            const int c = cw + mt * 16 + q * 4 + reg;
            if (c < NC) {
                const float inv = sume[mt][reg];
                float* op = out + ((size_t)b * NC + c) * DIM + r;
#pragma unroll
                for (int nt = 0; nt < 8; ++nt)
                    op[nt * 16] = Oacc[mt][nt][reg] * inv;
            }
        }
    }
}

extern "C" void kernel_launch(void* const* d_in, const int* in_sizes, int n_in,
                              void* d_out, int out_size, void* d_ws, size_t ws_size,
                              hipStream_t stream) {
    const float* x = (const float*)d_in[0];   // (8, 2500, 128) fp32
    const float* U = (const float*)d_in[1];   // (8921, 128) fp32
    float* out = (float*)d_out;               // (8, 8921, 128) fp32
    const int nblocks = BATCH * ((NC + CT - 1) / CT);   // 560

    const size_t need = 2 * (size_t)BATCH * LPAD * DIM * sizeof(short);  // 10.5 MB
    if (ws_size >= need) {
        short* XB = (short*)d_ws;
        short* XT = XB + (size_t)BATCH * LPAD * DIM;
        lwa_prepass<<<dim3(BATCH * NCH), dim3(256), 0, stream>>>(x, XB, XT);
        lwa_main<<<dim3(nblocks), dim3(256), 0, stream>>>(XB, XT, U, out);
    } else {
        lwa_fallback<<<dim3(nblocks), dim3(256), 0, stream>>>(x, U, out);
    }
}